// Round 9
// baseline (130.939 us; speedup 1.0000x reference)
//
#include <hip/hip_runtime.h>

// Per-sample 3x3 conv as bf16 implicit GEMM, NHWC, SAME padding.
// x: (32,128,128,32) f32; params: (32, 9216+32) f32; out: (32,128,128,32) f32
//
// R9: kill the staging phase (it was ~50% of wall, serialized by barriers).
//  - x staged as FP32 directly to LDS via global_load_lds width=16 (no VGPR
//    round-trip, no pack VALU, no ds_write). bf16 conversion moved into the
//    compute phase (v_cvt_pk_bf16_f32, VALU was 92% idle there).
//  - Block = 64-col strip x 16 output rows (4 tiles of 4 rows). Per tile
//    stage 6 input rows (55 KB LDS, single buffer); next tile's DMA issued
//    right after the compute barrier; 2 blocks/CU cover the latency.
//  - LDS chunk swizzle k ^= (col&7): both DMA writes (via pre-swizzled
//    GLOBAL source, linear LDS dest - G21/m173) and the stride-128B
//    fragment reads become 2-way bank aliased = free.
// Kept: swapped mfma(W,X)->D^T epilogue (dwordx4 stores); wprep W->bf16
// fragment layout in d_ws.

typedef __attribute__((ext_vector_type(8))) short bf16x8;
typedef __attribute__((ext_vector_type(4))) float f32x4;
typedef __attribute__((ext_vector_type(4))) int   i32x4;

constexpr int HWD  = 128, CINC = 32, FC = 32;
constexpr int WSZ  = 9 * CINC * FC;         // 9216
constexpr int PSTR = WSZ + FC;              // 9248

// LDS: 6 row-slots; row-slot = 66 window cols x 8 fp32 chunks(16B) = 528
// chunks, padded to 576 (9216 B) so any stray partial-wave DMA hits pad.
constexpr int ROW_CHUNKS = 528;
constexpr int ROW_BYTES  = 576 * 16;        // 9216
constexpr int LDS_BYTES  = 6 * ROW_BYTES;   // 55296

constexpr size_t WS_NEED = 32ull * 36 * 32 * 16;   // 589,824 B

// exact RNE pack (prep kernel only)
__device__ __forceinline__ unsigned short f2bf(float f) {
    unsigned u = __float_as_uint(f);
    return (unsigned short)((u + 0x7FFFu + ((u >> 16) & 1u)) >> 16);
}
__device__ __forceinline__ bf16x8 pack8(float4 a, float4 b) {
    bf16x8 r;
    r[0] = (short)f2bf(a.x); r[1] = (short)f2bf(a.y);
    r[2] = (short)f2bf(a.z); r[3] = (short)f2bf(a.w);
    r[4] = (short)f2bf(b.x); r[5] = (short)f2bf(b.y);
    r[6] = (short)f2bf(b.z); r[7] = (short)f2bf(b.w);
    return r;
}

// fp32x8 -> bf16x8 via v_cvt_pk_bf16_f32 (RNE, 4 instrs)
__device__ __forceinline__ bf16x8 cvtpk8(float4 lo, float4 hi) {
    union { i32x4 i; bf16x8 h; } u;
    asm("v_cvt_pk_bf16_f32 %0, %1, %2" : "=v"(u.i.x) : "v"(lo.x), "v"(lo.y));
    asm("v_cvt_pk_bf16_f32 %0, %1, %2" : "=v"(u.i.y) : "v"(lo.z), "v"(lo.w));
    asm("v_cvt_pk_bf16_f32 %0, %1, %2" : "=v"(u.i.z) : "v"(hi.x), "v"(hi.y));
    asm("v_cvt_pk_bf16_f32 %0, %1, %2" : "=v"(u.i.w) : "v"(hi.z), "v"(hi.w));
    return u.h;
}

__device__ __forceinline__ void dma16(const void* src, void* lds_dst) {
    __builtin_amdgcn_global_load_lds(
        (const __attribute__((address_space(1))) unsigned int*)src,
        (__attribute__((address_space(3))) unsigned int*)lds_dst, 16, 0, 0);
}

// ---------------- prep: per-sample W fp32 -> bf16 fragment layout ----------
// ws[b*1152 + (s*4+lg)*32 + n*16 + li] (bf16x8) = W[k=(s*4+lg)*8..+7][n*16+li]
__global__ __launch_bounds__(256) void wprep(
    const float* __restrict__ params, bf16x8* __restrict__ ws)
{
    const int b   = blockIdx.y;
    const int seg = blockIdx.x;      // 0..3
    const float* __restrict__ pw = params + (size_t)b * PSTR;
    #pragma unroll
    for (int i = 0; i < 2; ++i) {
        const int idx = threadIdx.x + i * 256;
        if (idx < 288) {
            const int c  = seg * 288 + idx;
            const int sg = c >> 5;
            const int f  = c & 31;
            const float* p = pw + (size_t)(sg * 8) * FC + f;
            float4 a, bb;
            a.x  = p[0 * FC]; a.y  = p[1 * FC]; a.z  = p[2 * FC]; a.w  = p[3 * FC];
            bb.x = p[4 * FC]; bb.y = p[5 * FC]; bb.z = p[6 * FC]; bb.w = p[7 * FC];
            ws[(size_t)b * 1152 + c] = pack8(a, bb);
        }
    }
}

// ---------------- main ----------------
template<bool USE_WS>
__global__ __launch_bounds__(256, 2) void conv3x3_mfma(
    const float* __restrict__ x, const float* __restrict__ params,
    float* __restrict__ out, const bf16x8* __restrict__ ws)
{
    __shared__ __align__(16) unsigned char smem[LDS_BYTES];

    // 512 blocks (32 samples x 2 col-halves x 8 row-bands); XCD-bijective.
    const int hw   = blockIdx.x;
    const int swz  = (hw & 7) * 64 + (hw >> 3);
    const int b    = swz >> 4;
    const int half = (swz >> 3) & 1;
    const int band = swz & 7;
    const int X0   = half * 64;     // output col base of strip
    const int R0   = band * 16;     // output row base of band

    const int t  = threadIdx.x;
    const int wv = t >> 6;          // wave 0..3 (= output row within tile)
    const int ln = t & 63;
    const int lg = ln >> 4;         // ci-group / f-reg-group
    const int li = ln & 15;         // px within 16-group / f within n-tile

    const float* __restrict__ xb = x + (size_t)b * (HWD * HWD * CINC);
    const float* __restrict__ pw = params + (size_t)b * PSTR;
    const size_t wsb = (size_t)b * 1152 + lg * 32;

    const float4 bias0 = *(const float4*)(pw + WSZ + lg * 4);
    const float4 bias1 = *(const float4*)(pw + WSZ + 16 + lg * 4);

    // ---- DMA stage: 6 input rows (y0t-1..y0t+4), 9 segs/row, wave-cyclic.
    // LDS slot s (in row rr) holds global chunk k = (s&7)^(col&7), col=s>>3.
    auto stage = [&](int y0t) {
        #pragma unroll
        for (int j = 0; j < 14; ++j) {
            const int d = wv + j * 4;
            if (d < 54) {
                const int rr  = d / 9;
                const int seg = d - rr * 9;
                const int s   = seg * 64 + ln;
                if (s < ROW_CHUNKS) {
                    const int col = s >> 3;
                    const int k   = (s & 7) ^ (col & 7);
                    const int iy  = y0t - 1 + rr;
                    const int gx  = X0 - 1 + col;
                    const bool ok = ((unsigned)iy < 128u) && ((unsigned)gx < 128u);
                    const float* src = ok ? (xb + ((size_t)iy * HWD + gx) * CINC + k * 4)
                                          : xb;   // clamped safe addr
                    dma16(src, smem + rr * ROW_BYTES + seg * 1024);
                }
            }
        }
    };
    // zero the slots whose DMA source was out-of-range (SAME padding)
    auto fixz = [&](int y0t) {
        #pragma unroll
        for (int j = 0; j < 14; ++j) {
            const int d = wv + j * 4;
            if (d < 54) {
                const int rr  = d / 9;
                const int seg = d - rr * 9;
                const int s   = seg * 64 + ln;
                if (s < ROW_CHUNKS) {
                    const int col = s >> 3;
                    const int iy  = y0t - 1 + rr;
                    const int gx  = X0 - 1 + col;
                    if (!(((unsigned)iy < 128u) && ((unsigned)gx < 128u))) {
                        i32x4 z = {0, 0, 0, 0};
                        *(i32x4*)(smem + rr * ROW_BYTES + s * 16) = z;
                    }
                }
            }
        }
    };

    // prologue: stage tile 0
    stage(R0);
    asm volatile("s_waitcnt vmcnt(0)" ::: "memory");
    fixz(R0);
    __syncthreads();

    for (int tt = 0; tt < 4; ++tt) {
        const int y0t = R0 + tt * 4;

        // ---- compute: wave -> 1 output row x 64 cols; swapped mfma(W,X)
        f32x4 acc[4][2];
        #pragma unroll
        for (int i = 0; i < 4; ++i) { acc[i][0] = (f32x4)0.0f; acc[i][1] = (f32x4)0.0f; }

        bf16x8 bc0, bc1;
        if constexpr (USE_WS) { bc0 = ws[wsb + li]; bc1 = ws[wsb + 16 + li]; }

        #pragma unroll
        for (int s9 = 0; s9 < 9; ++s9) {
            const int kh = s9 / 3, kw = s9 - 3 * (s9 / 3);
            bf16x8 b0, b1, bn0, bn1;
            if constexpr (USE_WS) {
                if (s9 < 8) {
                    bn0 = ws[wsb + (s9 + 1) * 128 + li];
                    bn1 = ws[wsb + (s9 + 1) * 128 + 16 + li];
                }
                b0 = bc0; b1 = bc1;
            } else {
                float w0[8], w1[8];
                #pragma unroll
                for (int kk = 0; kk < 8; ++kk) {
                    w0[kk] = pw[(size_t)(s9 * 32 + lg * 8 + kk) * FC + li];
                    w1[kk] = pw[(size_t)(s9 * 32 + lg * 8 + kk) * FC + 16 + li];
                }
                float4 a0{w0[0], w0[1], w0[2], w0[3]}, a1{w0[4], w0[5], w0[6], w0[7]};
                float4 c0{w1[0], w1[1], w1[2], w1[3]}, c1{w1[4], w1[5], w1[6], w1[7]};
                b0 = cvtpk8(a0, a1); b1 = cvtpk8(c0, c1);
            }
            const unsigned char* rowp = smem + (wv + kh) * ROW_BYTES;
            #pragma unroll
            for (int tI = 0; tI < 4; ++tI) {
                const int col = tI * 16 + li + kw;            // 0..65
                const int q0  = (2 * lg) ^ (col & 7);
                const float4 lo = *(const float4*)(rowp + col * 128 + q0 * 16);
                const float4 hi = *(const float4*)(rowp + col * 128 + (q0 ^ 1) * 16);
                const bf16x8 a  = cvtpk8(lo, hi);
                acc[tI][0] = __builtin_amdgcn_mfma_f32_16x16x32_bf16(b0, a, acc[tI][0], 0, 0, 0);
                acc[tI][1] = __builtin_amdgcn_mfma_f32_16x16x32_bf16(b1, a, acc[tI][1], 0, 0, 0);
            }
            if constexpr (USE_WS) { bc0 = bn0; bc1 = bn1; }
        }

        __syncthreads();                 // window fully consumed
        if (tt < 3) stage(y0t + 4);      // DMA next tile (overlaps epilogue)

        // ---- epilogue: lane holds f = n*16 + lg*4 + reg, px = tI*16 + li
        const int R = y0t + wv;
        float* __restrict__ ob = out + ((size_t)(b * HWD + R) * HWD + X0) * FC;
        #pragma unroll
        for (int tI = 0; tI < 4; ++tI) {
            float* q = ob + (size_t)(tI * 16 + li) * FC + lg * 4;
            float4 v0, v1;
            v0.x = acc[tI][0][0] + bias0.x; v0.y = acc[tI][0][1] + bias0.y;
            v0.z = acc[tI][0][2] + bias0.z; v0.w = acc[tI][0][3] + bias0.w;
            v1.x = acc[tI][1][0] + bias1.x; v1.y = acc[tI][1][1] + bias1.y;
            v1.z = acc[tI][1][2] + bias1.z; v1.w = acc[tI][1][3] + bias1.w;
            *(float4*)(q)      = v0;
            *(float4*)(q + 16) = v1;
        }

        if (tt < 3) {
            asm volatile("s_waitcnt vmcnt(0)" ::: "memory");
            fixz(y0t + 4);
            __syncthreads();             // window ready for next tile
        }
    }
}

extern "C" void kernel_launch(void* const* d_in, const int* in_sizes, int n_in,
                              void* d_out, int out_size, void* d_ws, size_t ws_size,
                              hipStream_t stream)
{
    const float* x      = (const float*)d_in[0];
    const float* params = (const float*)d_in[1];
    float*       out    = (float*)d_out;

    if (ws_size >= WS_NEED && d_ws != nullptr) {
        bf16x8* ws = (bf16x8*)d_ws;
        hipLaunchKernelGGL(wprep, dim3(4, 32), dim3(256), 0, stream, params, ws);
        hipLaunchKernelGGL((conv3x3_mfma<true>), dim3(512), dim3(256), 0, stream,
                           x, params, out, (const bf16x8*)ws);
    } else {
        hipLaunchKernelGGL((conv3x3_mfma<false>), dim3(512), dim3(256), 0, stream,
                           x, params, out, (const bf16x8*)nullptr);
    }
}